// Round 3
// baseline (899.091 us; speedup 1.0000x reference)
//
#include <hip/hip_runtime.h>

// Depth-dependent circle-of-confusion box-average, left/right views.
// Gather: dest (Y,X) left view sums sources with |Y-y|<=R, 0<=x-X<=2R,
// R = floor(depth) in 0..7.  Weight identity (R integer-valued):
//   [R>=ady]*[R>=hdx] = sat01(R + 1 - max(ady,hdx))
// R3 structure: sy loop ROLLED (body ~6KB, stays in 32KB L1I — R1/R2's fully
// unrolled ~75KB body was I-fetch bound), inner adx unrolled as hdx-pairs
// (adx in {2k-1,2k} shares hdx=k).  fp16 LDS texels kept (22KB -> 7 blocks/CU,
// ~7 waves/SIMD hides FMA dep chains).  Per texel: 1 cvt(R) + 4 clamped adds
// + 16 v_fma_mix_f32 (f16 rgb sources fused into the FMA).  All ds_read
// offsets are non-negative immediates off one per-sy base register.

typedef _Float16 h4 __attribute__((ext_vector_type(4)));

constexpr int Hh = 1024, Ww = 1024, Bb = 8, Cc = 3;
constexpr int RMAX = 7;                   // depth in [0,8)
constexpr int TW = 64, TH = 16, LJ = 4;   // dest tile 64x16, 4 Y-dests/thread
constexpr int HX = 2 * RMAX;              // 14
constexpr int HY = RMAX;                  // 7
constexpr int WCOLS = TW + 2 * HX;        // 92
constexpr int WROWS = TH + 2 * HY;        // 30

__device__ __forceinline__ float sat01(float x) {
  return fminf(fmaxf(x, 0.0f), 1.0f);     // folds to v_add_f32 clamp
}

__global__ __launch_bounds__(256)
void coc_gather(const float* __restrict__ img, const float* __restrict__ dep,
                float* __restrict__ out) {
  __shared__ h4 tile[WROWS * WCOLS];      // (r,g,b,R) fp16 ; 22080 B
  const int tx = threadIdx.x;             // 0..63 (dest X within tile)
  const int ty = threadIdx.y;             // 0..3
  const int tid = ty * 64 + tx;
  const int X0 = blockIdx.x * TW;
  const int Y0 = blockIdx.y * TH;
  const int b  = blockIdx.z;
  const size_t plane = (size_t)Hh * Ww;

  const float* db = dep + (size_t)b * plane;
  const float* ib = img + (size_t)b * Cc * plane;

  // ---- stage source window; OOB sentinel R=-1 makes all weights 0
  for (int idx = tid; idx < WROWS * WCOLS; idx += 256) {
    int lr = idx / WCOLS;
    int lc = idx - lr * WCOLS;
    int gy = Y0 - HY + lr;
    int gx = X0 - HX + lc;
    h4 v = {(_Float16)0.f, (_Float16)0.f, (_Float16)0.f, (_Float16)-1.f};
    if ((unsigned)gy < (unsigned)Hh && (unsigned)gx < (unsigned)Ww) {
      size_t p = (size_t)gy * Ww + gx;
      v.x = (_Float16)ib[p];
      v.y = (_Float16)ib[plane + p];
      v.z = (_Float16)ib[2 * plane + p];
      v.w = (_Float16)floorf(db[p]);      // integer-valued R, exact in fp16
    }
    tile[idx] = v;
  }
  __syncthreads();

  float4 aL[LJ], aR[LJ];                  // (cnt, r, g, b) per dest row, f32
  #pragma unroll
  for (int j = 0; j < LJ; ++j) {
    aL[j] = make_float4(0.f, 0.f, 0.f, 0.f);
    aR[j] = make_float4(0.f, 0.f, 0.f, 0.f);
  }

  const int lbase = ty * LJ;              // dest rows: Y0 + lbase + j

  #pragma unroll 1                        // KEEP ROLLED: body must fit L1I
  for (int sy = 0; sy < LJ + 2 * HY; ++sy) {        // 18 source rows
    const h4* row = &tile[(lbase + sy) * WCOLS + tx];  // leftmost tap = row[0]
    // per-j vertical threshold constants  cY[j] = 1 - |sy-7-j|  (runtime)
    float cY[LJ];
    #pragma unroll
    for (int j = 0; j < LJ; ++j) {
      int dy = sy - HY - j;
      int ady = dy < 0 ? -dy : dy;
      cY[j] = 1.0f - (float)ady;          // may be <= -7 => weight 0 (correct)
    }

    #pragma unroll
    for (int k = 0; k <= RMAX; ++k) {     // hdx value; adx in {2k-1, 2k}
      // fused thresholds c[j] = min(cY[j], 1-k)   (4 v_min_f32, shared by
      // the up-to-4 texels of this k-group)
      const float cX = 1.0f - (float)k;
      float c[LJ];
      #pragma unroll
      for (int j = 0; j < LJ; ++j) c[j] = fminf(cY[j], cX);

      #pragma unroll
      for (int s = 0; s < 2; ++s) {       // the two adx sharing hdx=k
        const int adx = 2 * k - 1 + s;    // k=0: adx -1(skip),0
        if (adx < 0 || adx > HX) continue;
        const h4 sL = row[HX + adx];      // left view  (dx = +adx)
        const h4 sR = row[HX - adx];      // right view (dx = -adx)
        const float RL = (float)sL.w;     // 1 cvt per texel
        const float RR = (float)sR.w;
        #pragma unroll
        for (int j = 0; j < LJ; ++j) {
          const float wL = sat01(RL + c[j]);   // v_add_f32 clamp
          const float wR = sat01(RR + c[j]);
          aL[j].x += wL;
          aL[j].y = fmaf(wL, (float)sL.x, aL[j].y);  // v_fma_mix_f32
          aL[j].z = fmaf(wL, (float)sL.y, aL[j].z);
          aL[j].w = fmaf(wL, (float)sL.z, aL[j].w);
          aR[j].x += wR;
          aR[j].y = fmaf(wR, (float)sR.x, aR[j].y);
          aR[j].z = fmaf(wR, (float)sR.y, aR[j].z);
          aR[j].w = fmaf(wR, (float)sR.z, aR[j].w);
        }
      }
    }
  }

  float* outL = out + (size_t)b * Cc * plane;
  float* outR = out + (size_t)(Bb + b) * Cc * plane;
  #pragma unroll
  for (int j = 0; j < LJ; ++j) {
    int Y = Y0 + lbase + j;
    size_t p = (size_t)Y * Ww + (X0 + tx);
    float invL = 1.0f / fmaxf(aL[j].x, 1.0f);
    float invR = 1.0f / fmaxf(aR[j].x, 1.0f);
    outL[p]             = fminf(fmaxf(aL[j].y * invL, 0.f), 1.f);
    outL[plane + p]     = fminf(fmaxf(aL[j].z * invL, 0.f), 1.f);
    outL[2 * plane + p] = fminf(fmaxf(aL[j].w * invL, 0.f), 1.f);
    outR[p]             = fminf(fmaxf(aR[j].y * invR, 0.f), 1.f);
    outR[plane + p]     = fminf(fmaxf(aR[j].z * invR, 0.f), 1.f);
    outR[2 * plane + p] = fminf(fmaxf(aR[j].w * invR, 0.f), 1.f);
  }
}

extern "C" void kernel_launch(void* const* d_in, const int* in_sizes, int n_in,
                              void* d_out, int out_size, void* d_ws, size_t ws_size,
                              hipStream_t stream) {
  const float* img = (const float*)d_in[0];   // (8,3,1024,1024) f32
  const float* dep = (const float*)d_in[1];   // (8,1024,1024) f32
  float* out = (float*)d_out;                 // left then right
  dim3 grid(Ww / TW, Hh / TH, Bb);            // 8192 blocks
  dim3 block(64, 4, 1);
  hipLaunchKernelGGL(coc_gather, grid, block, 0, stream, img, dep, out);
}

// Round 4
// 427.814 us; speedup vs baseline: 2.1016x; 2.1016x over previous
//
#include <hip/hip_runtime.h>

// Depth-dependent circle-of-confusion box-average, left/right views.
// R4: separable O(R)-per-pixel algorithm replacing the O(R^2) tap stencil.
//   Weight of source (y,x) for dest (Y,X): [R >= max(|y-Y|, hdx)] with
//   hdx = ceil(|x-X|/2), R = floor(depth) in 0..7.
// Vertical pass (per column x, per dest row Y), t = 0..7:
//   m_t = [R==t] * (r,g,b,1)                      (masked texel)
//   C_t(Y) = sum_{|dy|<=t} m_t[Y+dy]              (slides: +m_t[Y+t] - m_t[Y-1-t])
//   S_t(Y) = sum_{t'>=t} C_t'(Y) = sum_dy [R >= max(|dy|,t)] * v
// Horizontal gather (pure adds, weights pre-folded):
//   left(Y,X)  = S_0[X] + sum_k S_k[X+2k-1] + S_k[X+2k]
//   right(Y,X) = S_0[X] + sum_k S_k[X-2k+1] + S_k[X-2k]
// Thread = column owner; C_t in registers (f32); texels + S planes in LDS
// (fp16; cnt & masks exact, rgb quantization ~5e-4 relative).

typedef _Float16 h_t;
typedef _Float16 h4 __attribute__((ext_vector_type(4)));

constexpr int Hh = 1024, Ww = 1024, Bb = 8, Cc = 3;
constexpr int NCOL = 256;             // thread-columns per block
constexpr int HALO = 14;              // 2*RMAX x-halo
constexpr int TWD  = NCOL - 2 * HALO; // 228 dest columns per block
constexpr int STRIP = 32;             // dest rows per block
constexpr int RING = 17;              // texel ring rows (16 live + 1)

__device__ __forceinline__ float sat01(float x) {
  return fminf(fmaxf(x, 0.0f), 1.0f);
}

__device__ __forceinline__ int mod_ring(int y) {
  int m = y % RING;
  return m < 0 ? m + RING : m;
}

__global__ __launch_bounds__(256)
void coc_vsep(const float* __restrict__ img, const float* __restrict__ dep,
              float* __restrict__ out) {
  __shared__ h4 ring[RING * NCOL];    // 34816 B  (r,g,b,R), R=-1 sentinel OOB
  __shared__ h4 Sb[8 * NCOL];         // 16384 B  S_t planes for current row

  const int c  = threadIdx.x;         // 0..255, owns source column x
  const int X0 = blockIdx.x * TWD;
  const int Y0 = blockIdx.y * STRIP;
  const int b  = blockIdx.z;
  const int x  = X0 - HALO + c;
  const size_t plane = (size_t)Hh * Ww;
  const float* db = dep + (size_t)b * plane;
  const float* ib = img + (size_t)b * Cc * plane;

  auto stage = [&](int y) {
    h4 v = {(h_t)0.f, (h_t)0.f, (h_t)0.f, (h_t)-1.f};
    if ((unsigned)y < (unsigned)Hh && (unsigned)x < (unsigned)Ww) {
      size_t p = (size_t)y * Ww + x;
      v.x = (h_t)ib[p];
      v.y = (h_t)ib[plane + p];
      v.z = (h_t)ib[2 * plane + p];
      v.w = (h_t)floorf(db[p]);       // integer-valued R, exact in fp16
    }
    ring[mod_ring(y) * NCOL + c] = v;
  };

  // ---- prologue: rows [Y0-8, Y0+8]
  for (int y = Y0 - 8; y <= Y0 + 8; ++y) stage(y);
  __syncthreads();

  // ---- init C_t at virtual row Y0-1:  C_t = sum_{|d|<=t} m_t[Y0-1+d]
  float4 C[8];
  #pragma unroll
  for (int t = 0; t < 8; ++t) C[t] = make_float4(0.f, 0.f, 0.f, 0.f);
  #pragma unroll
  for (int d = -7; d <= 7; ++d) {
    h4 tx = ring[mod_ring(Y0 - 1 + d) * NCOL + c];
    float R = (float)tx.w;
    const int ad = d < 0 ? -d : d;
    #pragma unroll
    for (int t = ad; t < 8; ++t) {
      float m = sat01(1.0f - fabsf(R - (float)t));   // [R==t]
      C[t].x = fmaf(m, (float)tx.x, C[t].x);
      C[t].y = fmaf(m, (float)tx.y, C[t].y);
      C[t].z = fmaf(m, (float)tx.z, C[t].z);
      C[t].w += m;
    }
  }

  int sY = mod_ring(Y0);              // ring slot of current dest row
  for (int r = 0; r < STRIP; ++r) {
    const int Y = Y0 + r;

    // ---- A: slide C_t to row Y, suffix-sum into S_t, write to LDS
    #pragma unroll
    for (int t = 0; t < 8; ++t) {
      int si = sY + t;      si -= (si >= RING) ? RING : 0;   // row Y+t
      int so = sY - 1 - t;  so += (so < 0) ? RING : 0;       // row Y-1-t
      h4 ti = ring[si * NCOL + c];
      h4 to = ring[so * NCOL + c];
      float mi = sat01(1.0f - fabsf((float)ti.w - (float)t));
      float mo = sat01(1.0f - fabsf((float)to.w - (float)t));
      C[t].x = fmaf(mi, (float)ti.x, C[t].x);
      C[t].y = fmaf(mi, (float)ti.y, C[t].y);
      C[t].z = fmaf(mi, (float)ti.z, C[t].z);
      C[t].w += mi;
      C[t].x = fmaf(-mo, (float)to.x, C[t].x);
      C[t].y = fmaf(-mo, (float)to.y, C[t].y);
      C[t].z = fmaf(-mo, (float)to.z, C[t].z);
      C[t].w -= mo;
    }
    {
      float ax = 0.f, ay = 0.f, az = 0.f, aw = 0.f;
      #pragma unroll
      for (int t = 7; t >= 0; --t) {
        ax += C[t].x; ay += C[t].y; az += C[t].z; aw += C[t].w;
        h4 sv = {(h_t)ax, (h_t)ay, (h_t)az, (h_t)aw};
        Sb[t * NCOL + c] = sv;
      }
    }
    __syncthreads();

    // ---- B: horizontal gather for dest row Y (weights pre-folded: adds only)
    if (c < TWD && (X0 + c) < Ww) {
      const int a = c + HALO;         // dest's own column in the S array
      h4 s0 = Sb[0 * NCOL + a];
      float lx = (float)s0.x, ly = (float)s0.y, lz = (float)s0.z, lw = (float)s0.w;
      float rx = lx, ry = ly, rz = lz, rw = lw;
      #pragma unroll
      for (int k = 1; k <= 7; ++k) {  // imm-folded ds_read_b64 offsets
        h4 l0 = Sb[k * NCOL + a + 2 * k - 1];
        h4 l1 = Sb[k * NCOL + a + 2 * k];
        h4 r0 = Sb[k * NCOL + a - 2 * k];
        h4 r1 = Sb[k * NCOL + a - 2 * k + 1];
        lx += (float)l0.x + (float)l1.x;
        ly += (float)l0.y + (float)l1.y;
        lz += (float)l0.z + (float)l1.z;
        lw += (float)l0.w + (float)l1.w;
        rx += (float)r0.x + (float)r1.x;
        ry += (float)r0.y + (float)r1.y;
        rz += (float)r0.z + (float)r1.z;
        rw += (float)r0.w + (float)r1.w;
      }
      const int X = X0 + c;
      size_t p = (size_t)Y * Ww + X;
      float* outL = out + (size_t)b * Cc * plane;
      float* outR = out + (size_t)(Bb + b) * Cc * plane;
      float invL = 1.0f / fmaxf(lw, 1.0f);
      float invR = 1.0f / fmaxf(rw, 1.0f);
      outL[p]             = sat01(lx * invL);
      outL[plane + p]     = sat01(ly * invL);
      outL[2 * plane + p] = sat01(lz * invL);
      outR[p]             = sat01(rx * invR);
      outR[plane + p]     = sat01(ry * invR);
      outR[2 * plane + p] = sat01(rz * invR);
    }
    stage(Y + 9);                     // overwrites slot of row Y-8 (dead)
    __syncthreads();

    sY += 1; sY -= (sY >= RING) ? RING : 0;
  }
}

extern "C" void kernel_launch(void* const* d_in, const int* in_sizes, int n_in,
                              void* d_out, int out_size, void* d_ws, size_t ws_size,
                              hipStream_t stream) {
  const float* img = (const float*)d_in[0];   // (8,3,1024,1024) f32
  const float* dep = (const float*)d_in[1];   // (8,1024,1024) f32
  float* out = (float*)d_out;                 // left then right
  dim3 grid((Ww + TWD - 1) / TWD, Hh / STRIP, Bb);  // 5 x 32 x 8 = 1280 blocks
  dim3 block(NCOL, 1, 1);
  hipLaunchKernelGGL(coc_vsep, grid, block, 0, stream, img, dep, out);
}

// Round 5
// 418.101 us; speedup vs baseline: 2.1504x; 1.0232x over previous
//
#include <hip/hip_runtime.h>

// Depth-dependent circle-of-confusion box-average, left/right views.
// Separable O(R)-per-pixel algorithm (R4), R5: texel window moved from an
// LDS ring (%17 addressing, 16 ds_read_b64/row) into a REGISTER shift-ring
// (all indices compile-time). LDS now holds only the cross-thread S planes
// (16 KiB -> 8 blocks/CU; whole 1280-block grid co-resident, no tail round).
//   m_t = [R==t]*(r,g,b,1);  C_t(Y) = C_t(Y-1) + m_t[Y+t] - m_t[Y-1-t]
//   S_t = suffix_sum_t(C)  ->  left = S_0[a] + sum_k S_k[a+2k-1]+S_k[a+2k]
//                              right = S_0[a] + sum_k S_k[a-2k]+S_k[a-2k+1]

typedef _Float16 h_t;
typedef _Float16 h4 __attribute__((ext_vector_type(4)));

constexpr int Hh = 1024, Ww = 1024, Bb = 8, Cc = 3;
constexpr int NCOL = 256;             // thread-columns per block
constexpr int HALO = 14;              // 2*RMAX x-halo
constexpr int TWD  = NCOL - 2 * HALO; // 228 dest columns per block
constexpr int STRIP = 32;             // dest rows per block

__device__ __forceinline__ float sat01(float x) {
  return fminf(fmaxf(x, 0.0f), 1.0f);
}

__global__ __launch_bounds__(256)
void coc_vsep(const float* __restrict__ img, const float* __restrict__ dep,
              float* __restrict__ out) {
  __shared__ h4 Sb[8 * NCOL];         // 16384 B — the ONLY LDS

  const int c  = threadIdx.x;         // 0..255, owns source column x
  const int X0 = blockIdx.x * TWD;
  const int Y0 = blockIdx.y * STRIP;
  const int b  = blockIdx.z;
  const int x  = X0 - HALO + c;
  const size_t plane = (size_t)Hh * Ww;
  const float* db = dep + (size_t)b * plane;
  const float* ib = img + (size_t)b * Cc * plane;
  const bool xok = (unsigned)x < (unsigned)Ww;

  // register texel ring: slot d = source row Y-8+d (Y = current dest row)
  h4    Tc[16];                       // rgb (w unused)
  float Tr[16];                       // R = floor(depth); -1 OOB sentinel

  auto loadrow = [&](int y, h4& rgb, float& R) {
    rgb = (h4){(h_t)0.f, (h_t)0.f, (h_t)0.f, (h_t)0.f};
    R = -1.0f;
    if ((unsigned)y < (unsigned)Hh && xok) {
      size_t p = (size_t)y * Ww + x;
      rgb.x = (h_t)ib[p];
      rgb.y = (h_t)ib[plane + p];
      rgb.z = (h_t)ib[2 * plane + p];
      R = floorf(db[p]);              // integer-valued, exact
    }
  };

  #pragma unroll
  for (int d = 0; d < 16; ++d) loadrow(Y0 - 8 + d, Tc[d], Tr[d]);

  // init C_t at virtual dest row Y0-1: C_t = sum_{|d|<=t} m_t[Y0-1+d]
  float4 C[8];
  #pragma unroll
  for (int t = 0; t < 8; ++t) C[t] = make_float4(0.f, 0.f, 0.f, 0.f);
  #pragma unroll
  for (int d = -7; d <= 7; ++d) {
    const int i = 7 + d;              // ring slot of row Y0-1+d
    const int ad = d < 0 ? -d : d;
    #pragma unroll
    for (int t = ad; t < 8; ++t) {
      float m = sat01(1.0f - fabsf(Tr[i] - (float)t));   // [R==t]
      C[t].x = fmaf(m, (float)Tc[i].x, C[t].x);
      C[t].y = fmaf(m, (float)Tc[i].y, C[t].y);
      C[t].z = fmaf(m, (float)Tc[i].z, C[t].z);
      C[t].w += m;
    }
  }

  float* outL = out + (size_t)b * Cc * plane;
  float* outR = out + (size_t)(Bb + b) * Cc * plane;

  #pragma unroll 2
  for (int r = 0; r < STRIP; ++r) {
    const int Y = Y0 + r;
    h4 nc; float nr;
    loadrow(Y + 8, nc, nr);           // consumed at the bottom shift

    // ---- A: slide C_t to row Y (in: slot 8+t = row Y+t ; out: 7-t = Y-1-t)
    #pragma unroll
    for (int t = 0; t < 8; ++t) {
      const int ii = 8 + t, io = 7 - t;
      float mi = sat01(1.0f - fabsf(Tr[ii] - (float)t));
      float mo = sat01(1.0f - fabsf(Tr[io] - (float)t));
      C[t].x = fmaf(mi, (float)Tc[ii].x, C[t].x);
      C[t].y = fmaf(mi, (float)Tc[ii].y, C[t].y);
      C[t].z = fmaf(mi, (float)Tc[ii].z, C[t].z);
      C[t].w += mi;
      C[t].x = fmaf(-mo, (float)Tc[io].x, C[t].x);
      C[t].y = fmaf(-mo, (float)Tc[io].y, C[t].y);
      C[t].z = fmaf(-mo, (float)Tc[io].z, C[t].z);
      C[t].w -= mo;
    }

    // suffix-sum S_t = sum_{t'>=t} C_t' ; pack fp16 in registers
    h4 sv[8];
    {
      float ax = 0.f, ay = 0.f, az = 0.f, aw = 0.f;
      #pragma unroll
      for (int t = 7; t >= 0; --t) {
        ax += C[t].x; ay += C[t].y; az += C[t].z; aw += C[t].w;
        sv[t] = (h4){(h_t)ax, (h_t)ay, (h_t)az, (h_t)aw};
      }
    }

    __syncthreads();                  // prev-row B readers done with Sb
    #pragma unroll
    for (int t = 0; t < 8; ++t) Sb[t * NCOL + c] = sv[t];
    __syncthreads();                  // Sb ready

    // ---- B: horizontal gather (weights pre-folded: pure adds)
    if (c < TWD && (X0 + c) < Ww) {
      const int a = c + HALO;
      float4 L, Rv;
      {
        h4 s0 = Sb[a];
        L.x = (float)s0.x; L.y = (float)s0.y; L.z = (float)s0.z; L.w = (float)s0.w;
        Rv = L;
      }
      #pragma unroll
      for (int k = 1; k <= 7; ++k) {  // all imm-folded ds_read_b64
        h4 l0 = Sb[k * NCOL + a + 2 * k - 1];
        h4 l1 = Sb[k * NCOL + a + 2 * k];
        h4 r0 = Sb[k * NCOL + a - 2 * k];
        h4 r1 = Sb[k * NCOL + a - 2 * k + 1];
        L.x += (float)l0.x + (float)l1.x;
        L.y += (float)l0.y + (float)l1.y;
        L.z += (float)l0.z + (float)l1.z;
        L.w += (float)l0.w + (float)l1.w;
        Rv.x += (float)r0.x + (float)r1.x;
        Rv.y += (float)r0.y + (float)r1.y;
        Rv.z += (float)r0.z + (float)r1.z;
        Rv.w += (float)r0.w + (float)r1.w;
      }
      size_t p = (size_t)Y * Ww + (X0 + c);
      float invL = 1.0f / fmaxf(L.w, 1.0f);
      float invR = 1.0f / fmaxf(Rv.w, 1.0f);
      outL[p]             = sat01(L.x * invL);
      outL[plane + p]     = sat01(L.y * invL);
      outL[2 * plane + p] = sat01(L.z * invL);
      outR[p]             = sat01(Rv.x * invR);
      outR[plane + p]     = sat01(Rv.y * invR);
      outR[2 * plane + p] = sat01(Rv.z * invR);
    }

    // ---- shift register ring by one row (compile-time indices only)
    #pragma unroll
    for (int d = 0; d < 15; ++d) { Tc[d] = Tc[d + 1]; Tr[d] = Tr[d + 1]; }
    Tc[15] = nc; Tr[15] = nr;
  }
}

extern "C" void kernel_launch(void* const* d_in, const int* in_sizes, int n_in,
                              void* d_out, int out_size, void* d_ws, size_t ws_size,
                              hipStream_t stream) {
  const float* img = (const float*)d_in[0];   // (8,3,1024,1024) f32
  const float* dep = (const float*)d_in[1];   // (8,1024,1024) f32
  float* out = (float*)d_out;                 // left then right
  dim3 grid((Ww + TWD - 1) / TWD, Hh / STRIP, Bb);  // 5 x 32 x 8 = 1280 blocks
  dim3 block(NCOL, 1, 1);
  hipLaunchKernelGGL(coc_vsep, grid, block, 0, stream, img, dep, out);
}